// Round 16
// baseline (374.007 us; speedup 1.0000x reference)
//
#include <hip/hip_runtime.h>
#include <hip/hip_bf16.h>

static constexpr int Hd = 768;    // H
static constexpr int H2 = 1536;   // 2H
static constexpr int Cn = 64;     // C (labels)

typedef __attribute__((ext_vector_type(8))) short short8;
typedef __attribute__((ext_vector_type(8))) _Float16 half8;
typedef __attribute__((ext_vector_type(4))) float f32x4;
typedef unsigned short us;

__device__ inline unsigned int f2bf2(float a, float b) {
    __hip_bfloat162 h = __float22bfloat162_rn(float2{a, b});
    return *reinterpret_cast<unsigned int*>(&h);
}

__device__ inline void split1(float x, us& h, us& l) {
    __hip_bfloat16 hb = __float2bfloat16(x);
    float hf = __bfloat162float(hb);
    __hip_bfloat16 lb_ = __float2bfloat16(x - hf);
    h = *reinterpret_cast<us*>(&hb);
    l = *reinterpret_cast<us*>(&lb_);
}

__device__ inline us f2b(float x) {
    __hip_bfloat16 b = __float2bfloat16(x);
    return *reinterpret_cast<us*>(&b);
}

__device__ inline us f2h(float x) {
    _Float16 h = (_Float16)x;
    return *reinterpret_cast<us*>(&h);
}

__device__ inline float b2f(us u) {
    __hip_bfloat16 b = *reinterpret_cast<__hip_bfloat16*>(&u);
    return __bfloat162float(b);
}

// packed fp16 elementwise product: 4x v_pk_mul_f16
__device__ inline short8 hmul8(short8 a, short8 b) {
    half8 x = __builtin_bit_cast(half8, a);
    half8 y = __builtin_bit_cast(half8, b);
    half8 r = x * y;
    return __builtin_bit_cast(short8, r);
}

// XOR-swizzled element offset in a 128x32 16-bit tile: 2-way max on reads+writes
__device__ inline int swz(int row, int q) {
    return row * 32 + ((q ^ ((row >> 1) & 3)) << 3);
}

__device__ inline void gload16(const void* g, void* l) {
    __builtin_amdgcn_global_load_lds(
        (const __attribute__((address_space(1))) unsigned int*)g,
        (__attribute__((address_space(3))) unsigned int*)l, 16, 0, 0);
}

// ---------------- init: widx = -1 ----------------
__global__ void k_init(int* widx, int Wd) {
    int i = blockIdx.x * 256 + threadIdx.x;
    if (i < Wd) widx[i] = -1;
}

__global__ void k_scatter(const int* __restrict__ wmask, int* widx, int L, int Wd) {
    int i = blockIdx.x * 256 + threadIdx.x;
    if (i < L) {
        int m = wmask[i];
        if (m > 0 && m <= Wd) atomicMax(&widx[m - 1], i);  // last token wins
    }
}

// build we directly as hi/lo bf16 split
__global__ void k_build_we_split(const float4* __restrict__ tok, const int* __restrict__ widx,
                                 us* __restrict__ weh, us* __restrict__ wel, int Wd) {
    int i = blockIdx.x * 256 + threadIdx.x;   // over Wd * 192
    if (i >= Wd * 192) return;
    int w = i / 192, c4 = i - w * 192;
    int idx = widx[w];
    float4 v = (idx >= 0) ? tok[idx * 192 + c4] : float4{0.f, 0.f, 0.f, 0.f};
    us hh[4], ll[4];
    split1(v.x, hh[0], ll[0]);
    split1(v.y, hh[1], ll[1]);
    split1(v.z, hh[2], ll[2]);
    split1(v.w, hh[3], ll[3]);
    size_t o = (size_t)w * Hd + c4 * 4;
    *(ushort4*)&weh[o] = ushort4{hh[0], hh[1], hh[2], hh[3]};
    *(ushort4*)&wel[o] = ushort4{ll[0], ll[1], ll[2], ll[3]};
}

// ---------- batched transpose + split: T[n][k]; fmt=0 bf16 hi/lo, fmt=1 fp16 (Th only) ----------
struct TSArgs {
    const float* src[5];
    us* th[5];
    us* tl[5];
    int ld[5];
    int N[5];
    int fmt[5];
};
__global__ __launch_bounds__(256)
void k_tsplit(TSArgs a) {
    __shared__ float tile[64][65];
    const int z = blockIdx.z;
    const int n0 = blockIdx.x * 64, k0 = blockIdx.y * 64;
    if (n0 >= a.N[z]) return;
    const float* W = a.src[z];
    const int ld = a.ld[z];
    for (int idx = threadIdx.x; idx < 4096; idx += 256) {
        int kk = idx >> 6, nn = idx & 63;
        tile[kk][nn] = W[(size_t)(k0 + kk) * ld + n0 + nn];
    }
    __syncthreads();
    us* Th = a.th[z];
    us* Tl = a.tl[z];
    const int fmt = a.fmt[z];
    for (int idx = threadIdx.x; idx < 4096; idx += 256) {
        int nn = idx >> 6, kk = idx & 63;
        size_t o = (size_t)(n0 + nn) * Hd + k0 + kk;
        if (fmt) {
            Th[o] = f2h(tile[kk][nn]);
        } else {
            us h, l;
            split1(tile[kk][nn], h, l);
            Th[o] = h;
            Tl[o] = l;
        }
    }
}

// ---------- row-major hi/lo split ----------
__global__ __launch_bounds__(256)
void k_split(const float* __restrict__ x, int lda, int cols,
             us* __restrict__ h, us* __restrict__ l, int n4) {
    int i = blockIdx.x * 256 + threadIdx.x;
    if (i >= n4) return;
    int c4 = cols >> 2;
    int row = i / c4, cc = (i - row * c4) * 4;
    float4 v = *(const float4*)&x[(size_t)row * lda + cc];
    us hh[4], ll[4];
    split1(v.x, hh[0], ll[0]);
    split1(v.y, hh[1], ll[1]);
    split1(v.z, hh[2], ll[2]);
    split1(v.w, hh[3], ll[3]);
    size_t o = (size_t)row * cols + cc;
    *(ushort4*)&h[o] = ushort4{hh[0], hh[1], hh[2], hh[3]};
    *(ushort4*)&l[o] = ushort4{ll[0], ll[1], ll[2], ll[3]};
}

// ---------- split-bf16 GEMM, LDS double-buffered, K-split partials (small Ms) ----------
__global__ __launch_bounds__(256)
void k_gemm2(const us* __restrict__ Ah, const us* __restrict__ Al,
             const us* __restrict__ BhT, const us* __restrict__ BlT,
             float* __restrict__ Cpart, int M, int N, int K) {
    __shared__ __align__(16) us S[2][4][64 * 32];
    const int tid = threadIdx.x, wave = tid >> 6, lane = tid & 63;
    const int quad = lane >> 4, l15 = lane & 15;
    const int wm = wave & 1, wn = wave >> 1;
    const int m0 = blockIdx.y * 64, n0 = blockIdx.x * 64;
    const int Ks = K / gridDim.z, kbeg = blockIdx.z * Ks, kend = kbeg + Ks;
    float* C = Cpart + (size_t)blockIdx.z * M * N;

    const int srow = wave * 16 + (lane >> 2), soff = (lane & 3) * 8;
    const size_t gaB = (size_t)(m0 + srow) * K + soff;
    const size_t gbB = (size_t)(n0 + srow) * K + soff;
    const int lo = wave * 16 * 32;

    f32x4 acc[2][2];
#pragma unroll
    for (int a = 0; a < 2; ++a)
#pragma unroll
        for (int b = 0; b < 2; ++b) acc[a][b] = (f32x4){0.f, 0.f, 0.f, 0.f};

    auto stage = [&](int p, int k0) {
        gload16(Ah + gaB + k0, &S[p][0][lo]);
        gload16(Al + gaB + k0, &S[p][1][lo]);
        gload16(BhT + gbB + k0, &S[p][2][lo]);
        gload16(BlT + gbB + k0, &S[p][3][lo]);
    };

    int p = 0;
    stage(0, kbeg);
    for (int k0 = kbeg; k0 < kend; k0 += 32) {
        __syncthreads();
        if (k0 + 32 < kend) stage(p ^ 1, k0 + 32);
        short8 ah[2], al[2], bh[2], bl[2];
#pragma unroll
        for (int mt = 0; mt < 2; ++mt) {
            int off = (wm * 32 + mt * 16 + l15) * 32 + quad * 8;
            ah[mt] = *(const short8*)&S[p][0][off];
            al[mt] = *(const short8*)&S[p][1][off];
        }
#pragma unroll
        for (int nt = 0; nt < 2; ++nt) {
            int off = (wn * 32 + nt * 16 + l15) * 32 + quad * 8;
            bh[nt] = *(const short8*)&S[p][2][off];
            bl[nt] = *(const short8*)&S[p][3][off];
        }
#pragma unroll
        for (int mt = 0; mt < 2; ++mt)
#pragma unroll
            for (int nt = 0; nt < 2; ++nt) {
                acc[mt][nt] = __builtin_amdgcn_mfma_f32_16x16x32_bf16(al[mt], bh[nt], acc[mt][nt], 0, 0, 0);
                acc[mt][nt] = __builtin_amdgcn_mfma_f32_16x16x32_bf16(ah[mt], bl[nt], acc[mt][nt], 0, 0, 0);
                acc[mt][nt] = __builtin_amdgcn_mfma_f32_16x16x32_bf16(ah[mt], bh[nt], acc[mt][nt], 0, 0, 0);
            }
        p ^= 1;
    }
#pragma unroll
    for (int mt = 0; mt < 2; ++mt)
#pragma unroll
        for (int nt = 0; nt < 2; ++nt) {
            int col = n0 + wn * 32 + nt * 16 + l15;
#pragma unroll
            for (int reg = 0; reg < 4; ++reg) {
                int row = m0 + wm * 32 + mt * 16 + quad * 4 + reg;
                C[(size_t)row * N + col] = acc[mt][nt][reg];
            }
        }
}

// ---------- split-bf16 GEMM, z=1, fused outputs (bias + f32 / hi-lo split / 16-bit) ----------
__global__ __launch_bounds__(256)
void k_gemm3(const us* __restrict__ Ah, const us* __restrict__ Al,
             const us* __restrict__ BhT, const us* __restrict__ BlT,
             const float* __restrict__ bias, float* __restrict__ outF,
             us* __restrict__ sh, us* __restrict__ sl, us* __restrict__ bh16,
             int fp16out, int scols, int N, int K) {
    __shared__ __align__(16) us S[2][4][64 * 32];
    const int tid = threadIdx.x, wave = tid >> 6, lane = tid & 63;
    const int quad = lane >> 4, l15 = lane & 15;
    const int wm = wave & 1, wn = wave >> 1;
    const int m0 = blockIdx.y * 64, n0 = blockIdx.x * 64;

    const int srow = wave * 16 + (lane >> 2), soff = (lane & 3) * 8;
    const size_t gaB = (size_t)(m0 + srow) * K + soff;
    const size_t gbB = (size_t)(n0 + srow) * K + soff;
    const int lo = wave * 16 * 32;

    f32x4 acc[2][2];
#pragma unroll
    for (int a = 0; a < 2; ++a)
#pragma unroll
        for (int b = 0; b < 2; ++b) acc[a][b] = (f32x4){0.f, 0.f, 0.f, 0.f};

    auto stage = [&](int p, int k0) {
        gload16(Ah + gaB + k0, &S[p][0][lo]);
        gload16(Al + gaB + k0, &S[p][1][lo]);
        gload16(BhT + gbB + k0, &S[p][2][lo]);
        gload16(BlT + gbB + k0, &S[p][3][lo]);
    };

    int p = 0;
    stage(0, 0);
    for (int k0 = 0; k0 < K; k0 += 32) {
        __syncthreads();
        if (k0 + 32 < K) stage(p ^ 1, k0 + 32);
        short8 ah[2], al[2], bh[2], bl[2];
#pragma unroll
        for (int mt = 0; mt < 2; ++mt) {
            int off = (wm * 32 + mt * 16 + l15) * 32 + quad * 8;
            ah[mt] = *(const short8*)&S[p][0][off];
            al[mt] = *(const short8*)&S[p][1][off];
        }
#pragma unroll
        for (int nt = 0; nt < 2; ++nt) {
            int off = (wn * 32 + nt * 16 + l15) * 32 + quad * 8;
            bh[nt] = *(const short8*)&S[p][2][off];
            bl[nt] = *(const short8*)&S[p][3][off];
        }
#pragma unroll
        for (int mt = 0; mt < 2; ++mt)
#pragma unroll
            for (int nt = 0; nt < 2; ++nt) {
                acc[mt][nt] = __builtin_amdgcn_mfma_f32_16x16x32_bf16(al[mt], bh[nt], acc[mt][nt], 0, 0, 0);
                acc[mt][nt] = __builtin_amdgcn_mfma_f32_16x16x32_bf16(ah[mt], bl[nt], acc[mt][nt], 0, 0, 0);
                acc[mt][nt] = __builtin_amdgcn_mfma_f32_16x16x32_bf16(ah[mt], bh[nt], acc[mt][nt], 0, 0, 0);
            }
        p ^= 1;
    }
#pragma unroll
    for (int mt = 0; mt < 2; ++mt)
#pragma unroll
        for (int nt = 0; nt < 2; ++nt) {
            int col = n0 + wn * 32 + nt * 16 + l15;
            float bb = bias ? bias[col] : 0.f;
#pragma unroll
            for (int reg = 0; reg < 4; ++reg) {
                int row = m0 + wm * 32 + mt * 16 + quad * 4 + reg;
                float v = acc[mt][nt][reg] + bb;
                if (outF) outF[(size_t)row * N + col] = v;
                if (sh) {
                    if (col < scols) {
                        us h, l;
                        split1(v, h, l);
                        size_t o = (size_t)row * scols + col;
                        sh[o] = h;
                        sl[o] = l;
                    } else if (bh16) {
                        bh16[(size_t)row * scols + (col - scols)] = fp16out ? f2h(v) : f2b(v);
                    }
                }
            }
        }
}

// ---------- reduce partials + bias; f32 out + hi/lo split (col<scols) + 16-bit (col>=scols) ----------
__global__ __launch_bounds__(256)
void k_reduce(const float* __restrict__ part, int S, int MN, int N,
              const float* __restrict__ bias, float* __restrict__ outF,
              us* __restrict__ sh, us* __restrict__ sl, int scols,
              us* __restrict__ bh16, int fp16out) {
    int i = blockIdx.x * 256 + threadIdx.x;
    if (i >= MN) return;
    float v = 0.f;
    for (int s = 0; s < S; ++s) v += part[(size_t)s * MN + i];
    int row = i / N, col = i - row * N;
    if (bias) v += bias[col];
    if (outF) outF[i] = v;
    if (col < scols) {
        if (sh) {
            us h, l;
            split1(v, h, l);
            size_t o = (size_t)row * scols + col;
            sh[o] = h;
            sl[o] = l;
        }
    } else if (bh16) {
        bh16[(size_t)row * scols + (col - scols)] = fp16out ? f2h(v) : f2b(v);
    }
}

// ---------------- P-GEMM v9: A via LDS (fused fp16 scale), B frags direct L1/L2->VGPR ----------------
// R15 structure with Bs REMOVED: B-frags are per-lane b128 loads in exact MFMA
// layout, register-double-buffered one full k-step ahead (the A-path barrier
// still paces the loop). LDS ops/wave/k-step: 10 -> 6. LDS 34.3 -> 17.9 KB.
__global__ __launch_bounds__(256, 3)
void k_mfma9(const us* __restrict__ t1b,   // (1024,768) fp16
             const us* __restrict__ W1ct,  // (768,768) fp16 [j][k]
             const us* __restrict__ lb1b,  // (64,768) fp16
             const float* __restrict__ Aw, // (1024,768) f32
             const float* __restrict__ Bc, // (64,768) f32 (includes b1)
             const float* __restrict__ W2, // (768,3) f32
             float* __restrict__ scr) {    // (6,1024,64,3) f32 partials
    __shared__ __align__(16) us As[2][128 * 32];
    __shared__ float sred[128 * 3];

    const int tid = threadIdx.x, wave = tid >> 6, lane = tid & 63;
    const int quad = lane >> 4, l15 = lane & 15;
    const int wm = wave & 1, wn = wave >> 1;

    // L2-locality decode: b = xcd + 8*(jx*64 + c); my = xcd
    const int b = blockIdx.x;
    const int xcd = b & 7, slot = b >> 3;    // slot 0..383
    const int jx = slot >> 6;                // 0..5
    const int c = slot & 63;                 // 0..63 (varies fastest)
    const int my = xcd;                      // 0..7
    const int jt = jx * 128, m0 = my * 128;

    for (int i = tid; i < 128 * 3; i += 256) sred[i] = 0.f;

    // A staging map: thread -> row aro (0..127), 16 contiguous k at kbase
    const int aro = tid >> 1;
    const int qb = (tid & 1) * 2;
    const int kbase = qb * 8;
    const us* gA = W1ct + (size_t)(jt + aro) * Hd + kbase;
    const us* gL = lb1b + (size_t)c * Hd + kbase;
    const int w0 = swz(aro, qb), w1 = swz(aro, qb + 1);

    // B frag base: w-row = m0 + wn*64 + nt*16 + l15, k at quad*8
    const us* gBf = t1b + (size_t)(m0 + wn * 64 + l15) * Hd + quad * 8;

    f32x4 acc[4][4];
#pragma unroll
    for (int mt = 0; mt < 4; ++mt)
#pragma unroll
        for (int nt = 0; nt < 4; ++nt) acc[mt][nt] = (f32x4){0.f, 0.f, 0.f, 0.f};

    // A raw staging registers, two sets; B frag registers, two sets
    short8 aw0l, aw0h, al0l, al0h;
    short8 aw1l, aw1h, al1l, al1h;
    short8 bcur[4], bnxt[4];

    // prologue: A set0 <- k=0; A set1 <- k=32; B cur <- k=0; publish As[0]
    aw0l = *(const short8*)(gA + 0);  aw0h = *(const short8*)(gA + 8);
    al0l = *(const short8*)(gL + 0);  al0h = *(const short8*)(gL + 8);
    aw1l = *(const short8*)(gA + 32); aw1h = *(const short8*)(gA + 40);
    al1l = *(const short8*)(gL + 32); al1h = *(const short8*)(gL + 40);
#pragma unroll
    for (int nt = 0; nt < 4; ++nt)
        bcur[nt] = *(const short8*)(gBf + (size_t)nt * 16 * Hd);
    *(short8*)&As[0][w0] = hmul8(aw0l, al0l);
    *(short8*)&As[0][w1] = hmul8(aw0h, al0h);
    __syncthreads();

    for (int k = 0; k < Hd; k += 64) {
        // ---- step A: compute k (A from buf0, B from bcur) ----
        {
            short8 af[4];
#pragma unroll
            for (int mt = 0; mt < 4; ++mt)
                af[mt] = *(const short8*)&As[0][swz(wm * 64 + mt * 16 + l15, quad)];
            if (k + 64 < Hd) {            // prefetch raw A k+64 into set0
                aw0l = *(const short8*)(gA + k + 64); aw0h = *(const short8*)(gA + k + 72);
                al0l = *(const short8*)(gL + k + 64); al0h = *(const short8*)(gL + k + 72);
            }
#pragma unroll
            for (int nt = 0; nt < 4; ++nt)   // prefetch B frags k+32 (always valid)
                bnxt[nt] = *(const short8*)(gBf + (size_t)nt * 16 * Hd + k + 32);
#pragma unroll
            for (int mt = 0; mt < 4; ++mt)
#pragma unroll
                for (int nt = 0; nt < 4; ++nt)
                    acc[mt][nt] = __builtin_amdgcn_mfma_f32_16x16x32_f16(
                        __builtin_bit_cast(half8, af[mt]),
                        __builtin_bit_cast(half8, bcur[nt]), acc[mt][nt], 0, 0, 0);
            *(short8*)&As[1][w0] = hmul8(aw1l, al1l);   // scale+publish k+32
            *(short8*)&As[1][w1] = hmul8(aw1h, al1h);
            __syncthreads();
        }
        // ---- step B: compute k+32 (A from buf1, B from bnxt) ----
        {
            short8 af[4];
#pragma unroll
            for (int mt = 0; mt < 4; ++mt)
                af[mt] = *(const short8*)&As[1][swz(wm * 64 + mt * 16 + l15, quad)];
            if (k + 96 < Hd) {            // prefetch raw A k+96 into set1
                aw1l = *(const short8*)(gA + k + 96); aw1h = *(const short8*)(gA + k + 104);
                al1l = *(const short8*)(gL + k + 96); al1h = *(const short8*)(gL + k + 104);
            }
            if (k + 64 < Hd) {
#pragma unroll
                for (int nt = 0; nt < 4; ++nt)   // prefetch B frags k+64
                    bcur[nt] = *(const short8*)(gBf + (size_t)nt * 16 * Hd + k + 64);
            }
#pragma unroll
            for (int mt = 0; mt < 4; ++mt)
#pragma unroll
                for (int nt = 0; nt < 4; ++nt)
                    acc[mt][nt] = __builtin_amdgcn_mfma_f32_16x16x32_f16(
                        __builtin_bit_cast(half8, af[mt]),
                        __builtin_bit_cast(half8, bnxt[nt]), acc[mt][nt], 0, 0, 0);
            if (k + 64 < Hd) {
                *(short8*)&As[0][w0] = hmul8(aw0l, al0l);   // scale+publish k+64
                *(short8*)&As[0][w1] = hmul8(aw0h, al0h);
                __syncthreads();
            }
        }
    }

    // ---- epilogue: h = relu(P + Aw + Bc); sacc[w][r] += h*W2[j][r] ----
    // j = jt + wm*64 + mt*16 + quad*4 + reg ; w = m0 + wn*64 + nt*16 + l15
    float bcv[4][4], w2v[4][4][3];
#pragma unroll
    for (int mt = 0; mt < 4; ++mt) {
        const int jb = jt + wm * 64 + mt * 16 + quad * 4;
        float4 b4 = *(const float4*)&Bc[(size_t)c * Hd + jb];
        bcv[mt][0] = b4.x; bcv[mt][1] = b4.y; bcv[mt][2] = b4.z; bcv[mt][3] = b4.w;
#pragma unroll
        for (int reg = 0; reg < 4; ++reg)
#pragma unroll
            for (int r = 0; r < 3; ++r) w2v[mt][reg][r] = W2[(jb + reg) * 3 + r];
    }
#pragma unroll
    for (int nt = 0; nt < 4; ++nt) {
        const int w = m0 + wn * 64 + nt * 16 + l15;
        const float* awp = Aw + (size_t)w * Hd + jt + wm * 64;
        float s0 = 0.f, s1 = 0.f, s2 = 0.f;
#pragma unroll
        for (int mt = 0; mt < 4; ++mt) {
            float4 a4 = *(const float4*)&awp[mt * 16 + quad * 4];
            float av[4] = {a4.x, a4.y, a4.z, a4.w};
#pragma unroll
            for (int reg = 0; reg < 4; ++reg) {
                float h = acc[mt][nt][reg] + av[reg] + bcv[mt][reg];
                h = h > 0.f ? h : 0.f;
                s0 += h * w2v[mt][reg][0];
                s1 += h * w2v[mt][reg][1];
                s2 += h * w2v[mt][reg][2];
            }
        }
        s0 += __shfl_xor(s0, 16); s0 += __shfl_xor(s0, 32);
        s1 += __shfl_xor(s1, 16); s1 += __shfl_xor(s1, 32);
        s2 += __shfl_xor(s2, 16); s2 += __shfl_xor(s2, 32);
        if (quad == 0) {
            const int wl = wn * 64 + nt * 16 + l15;
            atomicAdd(&sred[wl * 3 + 0], s0);   // LDS, 2-way (wm)
            atomicAdd(&sred[wl * 3 + 1], s1);
            atomicAdd(&sred[wl * 3 + 2], s2);
        }
    }
    __syncthreads();
    // non-atomic store to per-jx scratch slot (disjoint across blocks)
    float* slab = scr + ((size_t)jx * 1024 * Cn + (size_t)m0 * Cn + c) * 3;
    for (int i = tid; i < 128 * 3; i += 256) {
        int wl = i / 3, r = i - wl * 3;
        slab[(size_t)wl * Cn * 3 + r] = sred[i];
    }
}

// ---------- final: out = b2 + sum_jx scr[jx] ----------
__global__ __launch_bounds__(256)
void k_scores(const float* __restrict__ scr, const float* __restrict__ b2,
              float* __restrict__ out, int n) {
    int i = blockIdx.x * 256 + threadIdx.x;
    if (i >= n) return;
    float v = b2[i % 3];
#pragma unroll
    for (int s = 0; s < 6; ++s) v += scr[(size_t)s * n + i];
    out[i] = v;
}

extern "C" void kernel_launch(void* const* d_in, const int* in_sizes, int n_in,
                              void* d_out, int out_size, void* d_ws, size_t ws_size,
                              hipStream_t stream) {
    const float* tok    = (const float*)d_in[0];
    const int*   wmask  = (const int*)d_in[1];
    const float* labe   = (const float*)d_in[3];
    const float* W_tok  = (const float*)d_in[4];
    const float* b_tok  = (const float*)d_in[5];
    const float* W_lab  = (const float*)d_in[6];
    const float* b_lab  = (const float*)d_in[7];
    const float* W1     = (const float*)d_in[8];
    const float* b1     = (const float*)d_in[9];
    const float* W2     = (const float*)d_in[10];
    const float* b2     = (const float*)d_in[11];
    float* out = (float*)d_out;

    const int L  = in_sizes[1];
    const int Wd = out_size / (Cn * 3);   // 1024

    char* ws = (char*)d_ws;
    size_t off = 0;
    auto alloc = [&](size_t bytes) { char* p = ws + off; off += (bytes + 255) & ~(size_t)255; return p; };
    // ---- persistent region ----
    int*   widx  = (int*)alloc(4096);
    float* Abuf  = (float*)alloc((size_t)Wd * Hd * 4);
    float* Bbuf  = (float*)alloc((size_t)Cn * Hd * 4);
    us* W1ct  = (us*)alloc((size_t)Hd * Hd * 2);   // fp16
    us* W1cl  = (us*)alloc((size_t)Hd * Hd * 2);   // unused
    us* t1b   = (us*)alloc((size_t)Wd * Hd * 2);   // fp16
    us* lb1b  = (us*)alloc((size_t)Cn * Hd * 2);   // fp16
    float* scr = (float*)alloc((size_t)6 * Wd * Cn * 3 * 4);   // 4.72 MB partials
    // ---- scratch region ----
    us* WtTh  = (us*)alloc((size_t)H2 * Hd * 2);
    us* WtTl  = (us*)alloc((size_t)H2 * Hd * 2);
    us* WlTh  = (us*)alloc((size_t)H2 * Hd * 2);
    us* WlTl  = (us*)alloc((size_t)H2 * Hd * 2);
    us* W1aTh = (us*)alloc((size_t)Hd * Hd * 2);
    us* W1aTl = (us*)alloc((size_t)Hd * Hd * 2);
    us* W1bTh = (us*)alloc((size_t)Hd * Hd * 2);
    us* W1bTl = (us*)alloc((size_t)Hd * Hd * 2);
    us* weh   = (us*)alloc((size_t)Wd * Hd * 2);
    us* wel   = (us*)alloc((size_t)Wd * Hd * 2);
    us* lah   = (us*)alloc((size_t)Cn * Hd * 2);
    us* lal   = (us*)alloc((size_t)Cn * Hd * 2);
    us* t0h   = (us*)alloc((size_t)Wd * Hd * 2);
    us* t0l   = (us*)alloc((size_t)Wd * Hd * 2);
    us* lb0h  = (us*)alloc((size_t)Cn * Hd * 2);
    us* lb0l  = (us*)alloc((size_t)Cn * Hd * 2);
    float* part = (float*)alloc((size_t)8 * Cn * H2 * 4);

    // 1) init + scatter + we split
    k_init<<<(Wd + 255) / 256, 256, 0, stream>>>(widx, Wd);
    k_scatter<<<(L + 255) / 256, 256, 0, stream>>>(wmask, widx, L, Wd);
    k_build_we_split<<<(Wd * 192 + 255) / 256, 256, 0, stream>>>((const float4*)tok, widx, weh, wel, Wd);

    // 2) batched weight transpose+split (W1c -> fp16)
    TSArgs ts;
    ts.src[0] = W_tok;  ts.th[0] = WtTh;  ts.tl[0] = WtTl;  ts.ld[0] = H2; ts.N[0] = H2; ts.fmt[0] = 0;
    ts.src[1] = W_lab;  ts.th[1] = WlTh;  ts.tl[1] = WlTl;  ts.ld[1] = H2; ts.N[1] = H2; ts.fmt[1] = 0;
    ts.src[2] = W1;                         ts.th[2] = W1aTh; ts.tl[2] = W1aTl; ts.ld[2] = Hd; ts.N[2] = Hd; ts.fmt[2] = 0;
    ts.src[3] = W1 + (size_t)Hd * Hd;       ts.th[3] = W1bTh; ts.tl[3] = W1bTl; ts.ld[3] = Hd; ts.N[3] = Hd; ts.fmt[3] = 0;
    ts.src[4] = W1 + (size_t)2 * Hd * Hd;   ts.th[4] = W1ct;  ts.tl[4] = W1cl;  ts.ld[4] = Hd; ts.N[4] = Hd; ts.fmt[4] = 1;
    k_tsplit<<<dim3(H2 / 64, Hd / 64, 5), 256, 0, stream>>>(ts);

    // 3) label emb split
    k_split<<<(Cn * Hd / 4 + 255) / 256, 256, 0, stream>>>(labe, Hd, Hd, lah, lal, Cn * Hd / 4);

    // 4) t = we @ W_tok + b_tok -> fused t0 hi/lo + t1b fp16
    k_gemm3<<<dim3(H2 / 64, Wd / 64), 256, 0, stream>>>(weh, wel, WtTh, WtTl, b_tok,
                                                        nullptr, t0h, t0l, t1b, 1, Hd, H2, Hd);

    // 5) lb = labe @ W_lab + b_lab (64x1536), z=8 -> reduce (lb0 split + lb1b fp16)
    k_gemm2<<<dim3(H2 / 64, 1, 8), 256, 0, stream>>>(lah, lal, WlTh, WlTl, part, Cn, H2, Hd);
    k_reduce<<<(Cn * H2 + 255) / 256, 256, 0, stream>>>(part, 8, Cn * H2, H2, b_lab, nullptr, lb0h, lb0l, Hd, lb1b, 1);

    // 6) Aw = t0 @ W1a (1024x768) -> fused f32 write
    k_gemm3<<<dim3(Hd / 64, Wd / 64), 256, 0, stream>>>(t0h, t0l, W1aTh, W1aTl, nullptr,
                                                        Abuf, nullptr, nullptr, nullptr, 0, 0, Hd, Hd);

    // 7) Bc = lb0 @ W1b + b1 (64x768), z=8 -> reduce
    k_gemm2<<<dim3(Hd / 64, 1, 8), 256, 0, stream>>>(lb0h, lb0l, W1bTh, W1bTl, part, Cn, Hd, Hd);
    k_reduce<<<(Cn * Hd + 255) / 256, 256, 0, stream>>>(part, 8, Cn * Hd, Hd, b1, Bbuf, nullptr, nullptr, Hd, nullptr, 0);

    // 8) fused fp16 P-GEMM, B-direct (all 64 c, one dispatch, L2-locality decode) -> scratch
    k_mfma9<<<3072, 256, 0, stream>>>(t1b, W1ct, lb1b, Abuf, Bbuf, W2, scr);

    // 9) out = b2 + sum_jx scr
    k_scores<<<(Wd * Cn * 3 + 255) / 256, 256, 0, stream>>>(scr, b2, out, Wd * Cn * 3);
}

// Round 17
// 274.295 us; speedup vs baseline: 1.3635x; 1.3635x over previous
//
#include <hip/hip_runtime.h>
#include <hip/hip_bf16.h>

static constexpr int Hd = 768;    // H
static constexpr int H2 = 1536;   // 2H
static constexpr int Cn = 64;     // C (labels)

typedef __attribute__((ext_vector_type(8))) short short8;
typedef __attribute__((ext_vector_type(8))) _Float16 half8;
typedef __attribute__((ext_vector_type(4))) float f32x4;
typedef unsigned short us;

__device__ inline unsigned int f2bf2(float a, float b) {
    __hip_bfloat162 h = __float22bfloat162_rn(float2{a, b});
    return *reinterpret_cast<unsigned int*>(&h);
}

__device__ inline void split1(float x, us& h, us& l) {
    __hip_bfloat16 hb = __float2bfloat16(x);
    float hf = __bfloat162float(hb);
    __hip_bfloat16 lb_ = __float2bfloat16(x - hf);
    h = *reinterpret_cast<us*>(&hb);
    l = *reinterpret_cast<us*>(&lb_);
}

__device__ inline us f2b(float x) {
    __hip_bfloat16 b = __float2bfloat16(x);
    return *reinterpret_cast<us*>(&b);
}

__device__ inline us f2h(float x) {
    _Float16 h = (_Float16)x;
    return *reinterpret_cast<us*>(&h);
}

__device__ inline float b2f(us u) {
    __hip_bfloat16 b = *reinterpret_cast<__hip_bfloat16*>(&u);
    return __bfloat162float(b);
}

// packed fp16 elementwise product: 4x v_pk_mul_f16
__device__ inline short8 hmul8(short8 a, short8 b) {
    half8 x = __builtin_bit_cast(half8, a);
    half8 y = __builtin_bit_cast(half8, b);
    half8 r = x * y;
    return __builtin_bit_cast(short8, r);
}

// XOR-swizzled element offset in a 128x32 16-bit tile: 2-way max on reads+writes
__device__ inline int swz(int row, int q) {
    return row * 32 + ((q ^ ((row >> 1) & 3)) << 3);
}

__device__ inline void gload16(const void* g, void* l) {
    __builtin_amdgcn_global_load_lds(
        (const __attribute__((address_space(1))) unsigned int*)g,
        (__attribute__((address_space(3))) unsigned int*)l, 16, 0, 0);
}

// ---------------- init: widx = -1 ----------------
__global__ void k_init(int* widx, int Wd) {
    int i = blockIdx.x * 256 + threadIdx.x;
    if (i < Wd) widx[i] = -1;
}

__global__ void k_scatter(const int* __restrict__ wmask, int* widx, int L, int Wd) {
    int i = blockIdx.x * 256 + threadIdx.x;
    if (i < L) {
        int m = wmask[i];
        if (m > 0 && m <= Wd) atomicMax(&widx[m - 1], i);  // last token wins
    }
}

// build we directly as hi/lo bf16 split
__global__ void k_build_we_split(const float4* __restrict__ tok, const int* __restrict__ widx,
                                 us* __restrict__ weh, us* __restrict__ wel, int Wd) {
    int i = blockIdx.x * 256 + threadIdx.x;   // over Wd * 192
    if (i >= Wd * 192) return;
    int w = i / 192, c4 = i - w * 192;
    int idx = widx[w];
    float4 v = (idx >= 0) ? tok[idx * 192 + c4] : float4{0.f, 0.f, 0.f, 0.f};
    us hh[4], ll[4];
    split1(v.x, hh[0], ll[0]);
    split1(v.y, hh[1], ll[1]);
    split1(v.z, hh[2], ll[2]);
    split1(v.w, hh[3], ll[3]);
    size_t o = (size_t)w * Hd + c4 * 4;
    *(ushort4*)&weh[o] = ushort4{hh[0], hh[1], hh[2], hh[3]};
    *(ushort4*)&wel[o] = ushort4{ll[0], ll[1], ll[2], ll[3]};
}

// ---------- batched transpose + split: T[n][k]; fmt=0 bf16 hi/lo, fmt=1 fp16 (Th only) ----------
struct TSArgs {
    const float* src[5];
    us* th[5];
    us* tl[5];
    int ld[5];
    int N[5];
    int fmt[5];
};
__global__ __launch_bounds__(256)
void k_tsplit(TSArgs a) {
    __shared__ float tile[64][65];
    const int z = blockIdx.z;
    const int n0 = blockIdx.x * 64, k0 = blockIdx.y * 64;
    if (n0 >= a.N[z]) return;
    const float* W = a.src[z];
    const int ld = a.ld[z];
    for (int idx = threadIdx.x; idx < 4096; idx += 256) {
        int kk = idx >> 6, nn = idx & 63;
        tile[kk][nn] = W[(size_t)(k0 + kk) * ld + n0 + nn];
    }
    __syncthreads();
    us* Th = a.th[z];
    us* Tl = a.tl[z];
    const int fmt = a.fmt[z];
    for (int idx = threadIdx.x; idx < 4096; idx += 256) {
        int nn = idx >> 6, kk = idx & 63;
        size_t o = (size_t)(n0 + nn) * Hd + k0 + kk;
        if (fmt) {
            Th[o] = f2h(tile[kk][nn]);
        } else {
            us h, l;
            split1(tile[kk][nn], h, l);
            Th[o] = h;
            Tl[o] = l;
        }
    }
}

// ---------- row-major hi/lo split ----------
__global__ __launch_bounds__(256)
void k_split(const float* __restrict__ x, int lda, int cols,
             us* __restrict__ h, us* __restrict__ l, int n4) {
    int i = blockIdx.x * 256 + threadIdx.x;
    if (i >= n4) return;
    int c4 = cols >> 2;
    int row = i / c4, cc = (i - row * c4) * 4;
    float4 v = *(const float4*)&x[(size_t)row * lda + cc];
    us hh[4], ll[4];
    split1(v.x, hh[0], ll[0]);
    split1(v.y, hh[1], ll[1]);
    split1(v.z, hh[2], ll[2]);
    split1(v.w, hh[3], ll[3]);
    size_t o = (size_t)row * cols + cc;
    *(ushort4*)&h[o] = ushort4{hh[0], hh[1], hh[2], hh[3]};
    *(ushort4*)&l[o] = ushort4{ll[0], ll[1], ll[2], ll[3]};
}

// ---------- split-bf16 GEMM, LDS double-buffered, K-split partials ----------
__global__ __launch_bounds__(256)
void k_gemm2(const us* __restrict__ Ah, const us* __restrict__ Al,
             const us* __restrict__ BhT, const us* __restrict__ BlT,
             float* __restrict__ Cpart, int M, int N, int K) {
    __shared__ __align__(16) us S[2][4][64 * 32];
    const int tid = threadIdx.x, wave = tid >> 6, lane = tid & 63;
    const int quad = lane >> 4, l15 = lane & 15;
    const int wm = wave & 1, wn = wave >> 1;
    const int m0 = blockIdx.y * 64, n0 = blockIdx.x * 64;
    const int Ks = K / gridDim.z, kbeg = blockIdx.z * Ks, kend = kbeg + Ks;
    float* C = Cpart + (size_t)blockIdx.z * M * N;

    const int srow = wave * 16 + (lane >> 2), soff = (lane & 3) * 8;
    const size_t gaB = (size_t)(m0 + srow) * K + soff;
    const size_t gbB = (size_t)(n0 + srow) * K + soff;
    const int lo = wave * 16 * 32;

    f32x4 acc[2][2];
#pragma unroll
    for (int a = 0; a < 2; ++a)
#pragma unroll
        for (int b = 0; b < 2; ++b) acc[a][b] = (f32x4){0.f, 0.f, 0.f, 0.f};

    auto stage = [&](int p, int k0) {
        gload16(Ah + gaB + k0, &S[p][0][lo]);
        gload16(Al + gaB + k0, &S[p][1][lo]);
        gload16(BhT + gbB + k0, &S[p][2][lo]);
        gload16(BlT + gbB + k0, &S[p][3][lo]);
    };

    int p = 0;
    stage(0, kbeg);
    for (int k0 = kbeg; k0 < kend; k0 += 32) {
        __syncthreads();
        if (k0 + 32 < kend) stage(p ^ 1, k0 + 32);
        short8 ah[2], al[2], bh[2], bl[2];
#pragma unroll
        for (int mt = 0; mt < 2; ++mt) {
            int off = (wm * 32 + mt * 16 + l15) * 32 + quad * 8;
            ah[mt] = *(const short8*)&S[p][0][off];
            al[mt] = *(const short8*)&S[p][1][off];
        }
#pragma unroll
        for (int nt = 0; nt < 2; ++nt) {
            int off = (wn * 32 + nt * 16 + l15) * 32 + quad * 8;
            bh[nt] = *(const short8*)&S[p][2][off];
            bl[nt] = *(const short8*)&S[p][3][off];
        }
#pragma unroll
        for (int mt = 0; mt < 2; ++mt)
#pragma unroll
            for (int nt = 0; nt < 2; ++nt) {
                acc[mt][nt] = __builtin_amdgcn_mfma_f32_16x16x32_bf16(al[mt], bh[nt], acc[mt][nt], 0, 0, 0);
                acc[mt][nt] = __builtin_amdgcn_mfma_f32_16x16x32_bf16(ah[mt], bl[nt], acc[mt][nt], 0, 0, 0);
                acc[mt][nt] = __builtin_amdgcn_mfma_f32_16x16x32_bf16(ah[mt], bh[nt], acc[mt][nt], 0, 0, 0);
            }
        p ^= 1;
    }
#pragma unroll
    for (int mt = 0; mt < 2; ++mt)
#pragma unroll
        for (int nt = 0; nt < 2; ++nt) {
            int col = n0 + wn * 32 + nt * 16 + l15;
#pragma unroll
            for (int reg = 0; reg < 4; ++reg) {
                int row = m0 + wm * 32 + mt * 16 + quad * 4 + reg;
                C[(size_t)row * N + col] = acc[mt][nt][reg];
            }
        }
}

// ---------- reduce partials + bias; f32 out + hi/lo split (col<scols) + 16-bit (col>=scols) ----------
__global__ __launch_bounds__(256)
void k_reduce(const float* __restrict__ part, int S, int MN, int N,
              const float* __restrict__ bias, float* __restrict__ outF,
              us* __restrict__ sh, us* __restrict__ sl, int scols,
              us* __restrict__ bh16, int fp16out) {
    int i = blockIdx.x * 256 + threadIdx.x;
    if (i >= MN) return;
    float v = 0.f;
    for (int s = 0; s < S; ++s) v += part[(size_t)s * MN + i];
    int row = i / N, col = i - row * N;
    if (bias) v += bias[col];
    if (outF) outF[i] = v;
    if (col < scols) {
        if (sh) {
            us h, l;
            split1(v, h, l);
            size_t o = (size_t)row * scols + col;
            sh[o] = h;
            sl[o] = l;
        }
    } else if (bh16) {
        bh16[(size_t)row * scols + (col - scols)] = fp16out ? f2h(v) : f2b(v);
    }
}

// ---------------- P-GEMM v7c (R15-proven): fp16 operands, packed-mul fused lb1-scaling ----------------
// L2-locality decode, reg->LDS->MFMA single-barrier pipeline, XOR swizzle, 3 blocks/CU.
// NOTE: (256,4) spills (VGPR 64 < acc tile); B-direct-from-global regressed 3x (R6/R12/R16).
__global__ __launch_bounds__(256, 3)
void k_mfma7(const us* __restrict__ t1b,   // (1024,768) fp16
             const us* __restrict__ W1ct,  // (768,768) fp16 [j][k]
             const us* __restrict__ lb1b,  // (64,768) fp16
             const float* __restrict__ Aw, // (1024,768) f32
             const float* __restrict__ Bc, // (64,768) f32 (includes b1)
             const float* __restrict__ W2, // (768,3) f32
             float* __restrict__ scr) {    // (6,1024,64,3) f32 partials
    __shared__ __align__(16) us As[2][128 * 32];
    __shared__ __align__(16) us Bs[2][128 * 32];
    __shared__ float sred[128 * 3];

    const int tid = threadIdx.x, wave = tid >> 6, lane = tid & 63;
    const int quad = lane >> 4, l15 = lane & 15;
    const int wm = wave & 1, wn = wave >> 1;

    // L2-locality decode: b = xcd + 8*(jx*64 + c); my = xcd
    const int b = blockIdx.x;
    const int xcd = b & 7, slot = b >> 3;    // slot 0..383
    const int jx = slot >> 6;                // 0..5
    const int c = slot & 63;                 // 0..63 (varies fastest)
    const int my = xcd;                      // 0..7
    const int jt = jx * 128, m0 = my * 128;

    for (int i = tid; i < 128 * 3; i += 256) sred[i] = 0.f;

    // staging map: thread -> row aro (0..127), 16 contiguous k at kbase
    const int aro = tid >> 1;
    const int qb = (tid & 1) * 2;            // logical chunk pair {qb, qb+1}
    const int kbase = qb * 8;
    const us* gA = W1ct + (size_t)(jt + aro) * Hd + kbase;
    const us* gL = lb1b + (size_t)c * Hd + kbase;
    const us* gB = t1b + (size_t)(m0 + aro) * Hd + kbase;
    const int w0 = swz(aro, qb), w1 = swz(aro, qb + 1);

    f32x4 acc[4][4];
#pragma unroll
    for (int mt = 0; mt < 4; ++mt)
#pragma unroll
        for (int nt = 0; nt < 4; ++nt) acc[mt][nt] = (f32x4){0.f, 0.f, 0.f, 0.f};

    // raw staging registers, two sets
    short8 aw0l, aw0h, al0l, al0h, b0l, b0h;
    short8 aw1l, aw1h, al1l, al1h, b1l, b1h;

    // prologue: set0 <- k=0; set1 <- k=32; scale+publish set0 -> buf0
    aw0l = *(const short8*)(gA + 0);  aw0h = *(const short8*)(gA + 8);
    al0l = *(const short8*)(gL + 0);  al0h = *(const short8*)(gL + 8);
    b0l  = *(const short8*)(gB + 0);  b0h  = *(const short8*)(gB + 8);
    aw1l = *(const short8*)(gA + 32); aw1h = *(const short8*)(gA + 40);
    al1l = *(const short8*)(gL + 32); al1h = *(const short8*)(gL + 40);
    b1l  = *(const short8*)(gB + 32); b1h  = *(const short8*)(gB + 40);
    *(short8*)&As[0][w0] = hmul8(aw0l, al0l);
    *(short8*)&As[0][w1] = hmul8(aw0h, al0h);
    *(short8*)&Bs[0][w0] = b0l;
    *(short8*)&Bs[0][w1] = b0h;
    __syncthreads();

    for (int k = 0; k < Hd; k += 64) {
        // ---- step A: compute k from buf0; set1 holds raw k+32 ----
        {
            short8 af[4], bf[4];
#pragma unroll
            for (int mt = 0; mt < 4; ++mt)
                af[mt] = *(const short8*)&As[0][swz(wm * 64 + mt * 16 + l15, quad)];
#pragma unroll
            for (int nt = 0; nt < 4; ++nt)
                bf[nt] = *(const short8*)&Bs[0][swz(wn * 64 + nt * 16 + l15, quad)];
            if (k + 64 < Hd) {            // prefetch raw k+64 into set0
                aw0l = *(const short8*)(gA + k + 64); aw0h = *(const short8*)(gA + k + 72);
                al0l = *(const short8*)(gL + k + 64); al0h = *(const short8*)(gL + k + 72);
                b0l  = *(const short8*)(gB + k + 64); b0h  = *(const short8*)(gB + k + 72);
            }
#pragma unroll
            for (int mt = 0; mt < 4; ++mt)
#pragma unroll
                for (int nt = 0; nt < 4; ++nt)
                    acc[mt][nt] = __builtin_amdgcn_mfma_f32_16x16x32_f16(
                        __builtin_bit_cast(half8, af[mt]),
                        __builtin_bit_cast(half8, bf[nt]), acc[mt][nt], 0, 0, 0);
            *(short8*)&As[1][w0] = hmul8(aw1l, al1l);   // scale+publish k+32
            *(short8*)&As[1][w1] = hmul8(aw1h, al1h);
            *(short8*)&Bs[1][w0] = b1l;
            *(short8*)&Bs[1][w1] = b1h;
            __syncthreads();
        }
        // ---- step B: compute k+32 from buf1; set0 holds raw k+64 ----
        {
            short8 af[4], bf[4];
#pragma unroll
            for (int mt = 0; mt < 4; ++mt)
                af[mt] = *(const short8*)&As[1][swz(wm * 64 + mt * 16 + l15, quad)];
#pragma unroll
            for (int nt = 0; nt < 4; ++nt)
                bf[nt] = *(const short8*)&Bs[1][swz(wn * 64 + nt * 16 + l15, quad)];
            if (k + 96 < Hd) {            // prefetch raw k+96 into set1
                aw1l = *(const short8*)(gA + k + 96); aw1h = *(const short8*)(gA + k + 104);
                al1l = *(const short8*)(gL + k + 96); al1h = *(const short8*)(gL + k + 104);
                b1l  = *(const short8*)(gB + k + 96); b1h  = *(const short8*)(gB + k + 104);
            }
#pragma unroll
            for (int mt = 0; mt < 4; ++mt)
#pragma unroll
                for (int nt = 0; nt < 4; ++nt)
                    acc[mt][nt] = __builtin_amdgcn_mfma_f32_16x16x32_f16(
                        __builtin_bit_cast(half8, af[mt]),
                        __builtin_bit_cast(half8, bf[nt]), acc[mt][nt], 0, 0, 0);
            if (k + 64 < Hd) {
                *(short8*)&As[0][w0] = hmul8(aw0l, al0l);   // scale+publish k+64
                *(short8*)&As[0][w1] = hmul8(aw0h, al0h);
                *(short8*)&Bs[0][w0] = b0l;
                *(short8*)&Bs[0][w1] = b0h;
                __syncthreads();
            }
        }
    }

    // ---- epilogue: h = relu(P + Aw + Bc); sacc[w][r] += h*W2[j][r] ----
    // j = jt + wm*64 + mt*16 + quad*4 + reg ; w = m0 + wn*64 + nt*16 + l15
    float bcv[4][4], w2v[4][4][3];
#pragma unroll
    for (int mt = 0; mt < 4; ++mt) {
        const int jb = jt + wm * 64 + mt * 16 + quad * 4;
        float4 b4 = *(const float4*)&Bc[(size_t)c * Hd + jb];
        bcv[mt][0] = b4.x; bcv[mt][1] = b4.y; bcv[mt][2] = b4.z; bcv[mt][3] = b4.w;
#pragma unroll
        for (int reg = 0; reg < 4; ++reg)
#pragma unroll
            for (int r = 0; r < 3; ++r) w2v[mt][reg][r] = W2[(jb + reg) * 3 + r];
    }
#pragma unroll
    for (int nt = 0; nt < 4; ++nt) {
        const int w = m0 + wn * 64 + nt * 16 + l15;
        const float* awp = Aw + (size_t)w * Hd + jt + wm * 64;
        float s0 = 0.f, s1 = 0.f, s2 = 0.f;
#pragma unroll
        for (int mt = 0; mt < 4; ++mt) {
            float4 a4 = *(const float4*)&awp[mt * 16 + quad * 4];
            float av[4] = {a4.x, a4.y, a4.z, a4.w};
#pragma unroll
            for (int reg = 0; reg < 4; ++reg) {
                float h = acc[mt][nt][reg] + av[reg] + bcv[mt][reg];
                h = h > 0.f ? h : 0.f;
                s0 += h * w2v[mt][reg][0];
                s1 += h * w2v[mt][reg][1];
                s2 += h * w2v[mt][reg][2];
            }
        }
        s0 += __shfl_xor(s0, 16); s0 += __shfl_xor(s0, 32);
        s1 += __shfl_xor(s1, 16); s1 += __shfl_xor(s1, 32);
        s2 += __shfl_xor(s2, 16); s2 += __shfl_xor(s2, 32);
        if (quad == 0) {
            const int wl = wn * 64 + nt * 16 + l15;
            atomicAdd(&sred[wl * 3 + 0], s0);   // LDS, 2-way (wm)
            atomicAdd(&sred[wl * 3 + 1], s1);
            atomicAdd(&sred[wl * 3 + 2], s2);
        }
    }
    __syncthreads();
    // non-atomic store to per-jx scratch slot (disjoint across blocks)
    float* slab = scr + ((size_t)jx * 1024 * Cn + (size_t)m0 * Cn + c) * 3;
    for (int i = tid; i < 128 * 3; i += 256) {
        int wl = i / 3, r = i - wl * 3;
        slab[(size_t)wl * Cn * 3 + r] = sred[i];
    }
}

// ---------- final: out = b2 + sum_jx scr[jx] ----------
__global__ __launch_bounds__(256)
void k_scores(const float* __restrict__ scr, const float* __restrict__ b2,
              float* __restrict__ out, int n) {
    int i = blockIdx.x * 256 + threadIdx.x;
    if (i >= n) return;
    float v = b2[i % 3];
#pragma unroll
    for (int s = 0; s < 6; ++s) v += scr[(size_t)s * n + i];
    out[i] = v;
}

extern "C" void kernel_launch(void* const* d_in, const int* in_sizes, int n_in,
                              void* d_out, int out_size, void* d_ws, size_t ws_size,
                              hipStream_t stream) {
    const float* tok    = (const float*)d_in[0];
    const int*   wmask  = (const int*)d_in[1];
    const float* labe   = (const float*)d_in[3];
    const float* W_tok  = (const float*)d_in[4];
    const float* b_tok  = (const float*)d_in[5];
    const float* W_lab  = (const float*)d_in[6];
    const float* b_lab  = (const float*)d_in[7];
    const float* W1     = (const float*)d_in[8];
    const float* b1     = (const float*)d_in[9];
    const float* W2     = (const float*)d_in[10];
    const float* b2     = (const float*)d_in[11];
    float* out = (float*)d_out;

    const int L  = in_sizes[1];
    const int Wd = out_size / (Cn * 3);   // 1024

    char* ws = (char*)d_ws;
    size_t off = 0;
    auto alloc = [&](size_t bytes) { char* p = ws + off; off += (bytes + 255) & ~(size_t)255; return p; };
    // ---- persistent region ----
    int*   widx  = (int*)alloc(4096);
    float* Abuf  = (float*)alloc((size_t)Wd * Hd * 4);
    float* Bbuf  = (float*)alloc((size_t)Cn * Hd * 4);
    us* W1ct  = (us*)alloc((size_t)Hd * Hd * 2);   // fp16
    us* W1cl  = (us*)alloc((size_t)Hd * Hd * 2);   // unused
    us* t1b   = (us*)alloc((size_t)Wd * Hd * 2);   // fp16
    us* lb1b  = (us*)alloc((size_t)Cn * Hd * 2);   // fp16
    float* scr = (float*)alloc((size_t)6 * Wd * Cn * 3 * 4);   // 4.72 MB partials
    // ---- scratch region ----
    us* WtTh  = (us*)alloc((size_t)H2 * Hd * 2);
    us* WtTl  = (us*)alloc((size_t)H2 * Hd * 2);
    us* WlTh  = (us*)alloc((size_t)H2 * Hd * 2);
    us* WlTl  = (us*)alloc((size_t)H2 * Hd * 2);
    us* W1aTh = (us*)alloc((size_t)Hd * Hd * 2);
    us* W1aTl = (us*)alloc((size_t)Hd * Hd * 2);
    us* W1bTh = (us*)alloc((size_t)Hd * Hd * 2);
    us* W1bTl = (us*)alloc((size_t)Hd * Hd * 2);
    us* weh   = (us*)alloc((size_t)Wd * Hd * 2);
    us* wel   = (us*)alloc((size_t)Wd * Hd * 2);
    us* lah   = (us*)alloc((size_t)Cn * Hd * 2);
    us* lal   = (us*)alloc((size_t)Cn * Hd * 2);
    us* t0h   = (us*)alloc((size_t)Wd * Hd * 2);
    us* t0l   = (us*)alloc((size_t)Wd * Hd * 2);
    us* lb0h  = (us*)alloc((size_t)Cn * Hd * 2);
    us* lb0l  = (us*)alloc((size_t)Cn * Hd * 2);
    float* part = (float*)alloc((size_t)2 * Wd * H2 * 4);   // 12.6 MB (covers z=2 t-GEMM, z=8 label chains)

    // 1) init + scatter + we split
    k_init<<<(Wd + 255) / 256, 256, 0, stream>>>(widx, Wd);
    k_scatter<<<(L + 255) / 256, 256, 0, stream>>>(wmask, widx, L, Wd);
    k_build_we_split<<<(Wd * 192 + 255) / 256, 256, 0, stream>>>((const float4*)tok, widx, weh, wel, Wd);

    // 2) batched weight transpose+split (W1c -> fp16)
    TSArgs ts;
    ts.src[0] = W_tok;  ts.th[0] = WtTh;  ts.tl[0] = WtTl;  ts.ld[0] = H2; ts.N[0] = H2; ts.fmt[0] = 0;
    ts.src[1] = W_lab;  ts.th[1] = WlTh;  ts.tl[1] = WlTl;  ts.ld[1] = H2; ts.N[1] = H2; ts.fmt[1] = 0;
    ts.src[2] = W1;                         ts.th[2] = W1aTh; ts.tl[2] = W1aTl; ts.ld[2] = Hd; ts.N[2] = Hd; ts.fmt[2] = 0;
    ts.src[3] = W1 + (size_t)Hd * Hd;       ts.th[3] = W1bTh; ts.tl[3] = W1bTl; ts.ld[3] = Hd; ts.N[3] = Hd; ts.fmt[3] = 0;
    ts.src[4] = W1 + (size_t)2 * Hd * Hd;   ts.th[4] = W1ct;  ts.tl[4] = W1cl;  ts.ld[4] = Hd; ts.N[4] = Hd; ts.fmt[4] = 1;
    k_tsplit<<<dim3(H2 / 64, Hd / 64, 5), 256, 0, stream>>>(ts);

    // 3) label emb split
    k_split<<<(Cn * Hd / 4 + 255) / 256, 256, 0, stream>>>(labe, Hd, Hd, lah, lal, Cn * Hd / 4);

    // 4) t = we @ W_tok + b_tok (1024x1536), z=2 -> reduce (t0 hi/lo + t1b fp16)
    k_gemm2<<<dim3(H2 / 64, Wd / 64, 2), 256, 0, stream>>>(weh, wel, WtTh, WtTl, part, Wd, H2, Hd);
    k_reduce<<<(Wd * H2 + 255) / 256, 256, 0, stream>>>(part, 2, Wd * H2, H2, b_tok, nullptr, t0h, t0l, Hd, t1b, 1);

    // 5) lb = labe @ W_lab + b_lab (64x1536), z=8 -> reduce (lb0 split + lb1b fp16)
    k_gemm2<<<dim3(H2 / 64, 1, 8), 256, 0, stream>>>(lah, lal, WlTh, WlTl, part, Cn, H2, Hd);
    k_reduce<<<(Cn * H2 + 255) / 256, 256, 0, stream>>>(part, 8, Cn * H2, H2, b_lab, nullptr, lb0h, lb0l, Hd, lb1b, 1);

    // 6) Aw = t0 @ W1a (1024x768), z=2 -> reduce (f32)
    k_gemm2<<<dim3(Hd / 64, Wd / 64, 2), 256, 0, stream>>>(t0h, t0l, W1aTh, W1aTl, part, Wd, Hd, Hd);
    k_reduce<<<(Wd * Hd + 255) / 256, 256, 0, stream>>>(part, 2, Wd * Hd, Hd, nullptr, Abuf, nullptr, nullptr, Hd, nullptr, 0);

    // 7) Bc = lb0 @ W1b + b1 (64x768), z=8 -> reduce
    k_gemm2<<<dim3(Hd / 64, 1, 8), 256, 0, stream>>>(lb0h, lb0l, W1bTh, W1bTl, part, Cn, Hd, Hd);
    k_reduce<<<(Cn * Hd + 255) / 256, 256, 0, stream>>>(part, 8, Cn * Hd, Hd, b1, Bbuf, nullptr, nullptr, Hd, nullptr, 0);

    // 8) fused fp16 P-GEMM (all 64 c, one dispatch, L2-locality decode) -> scratch
    k_mfma7<<<3072, 256, 0, stream>>>(t1b, W1ct, lb1b, Abuf, Bbuf, W2, scr);

    // 9) out = b2 + sum_jx scr
    k_scores<<<(Wd * Cn * 3 + 255) / 256, 256, 0, stream>>>(scr, b2, out, Wd * Cn * 3);
}

// Round 18
// 264.957 us; speedup vs baseline: 1.4116x; 1.0352x over previous
//
#include <hip/hip_runtime.h>
#include <hip/hip_bf16.h>

static constexpr int Hd = 768;    // H
static constexpr int H2 = 1536;   // 2H
static constexpr int Cn = 64;     // C (labels)

typedef __attribute__((ext_vector_type(8))) short short8;
typedef __attribute__((ext_vector_type(8))) _Float16 half8;
typedef __attribute__((ext_vector_type(4))) float f32x4;
typedef unsigned short us;

__device__ inline unsigned int f2bf2(float a, float b) {
    __hip_bfloat162 h = __float22bfloat162_rn(float2{a, b});
    return *reinterpret_cast<unsigned int*>(&h);
}

__device__ inline void split1(float x, us& h, us& l) {
    __hip_bfloat16 hb = __float2bfloat16(x);
    float hf = __bfloat162float(hb);
    __hip_bfloat16 lb_ = __float2bfloat16(x - hf);
    h = *reinterpret_cast<us*>(&hb);
    l = *reinterpret_cast<us*>(&lb_);
}

__device__ inline us f2b(float x) {
    __hip_bfloat16 b = __float2bfloat16(x);
    return *reinterpret_cast<us*>(&b);
}

__device__ inline us f2h(float x) {
    _Float16 h = (_Float16)x;
    return *reinterpret_cast<us*>(&h);
}

__device__ inline float b2f(us u) {
    __hip_bfloat16 b = *reinterpret_cast<__hip_bfloat16*>(&u);
    return __bfloat162float(b);
}

// packed fp16 elementwise product: 4x v_pk_mul_f16
__device__ inline short8 hmul8(short8 a, short8 b) {
    half8 x = __builtin_bit_cast(half8, a);
    half8 y = __builtin_bit_cast(half8, b);
    half8 r = x * y;
    return __builtin_bit_cast(short8, r);
}

// XOR-swizzled element offset in a 128x32 16-bit tile: 2-way max on reads+writes
__device__ inline int swz(int row, int q) {
    return row * 32 + ((q ^ ((row >> 1) & 3)) << 3);
}

__device__ inline void gload16(const void* g, void* l) {
    __builtin_amdgcn_global_load_lds(
        (const __attribute__((address_space(1))) unsigned int*)g,
        (__attribute__((address_space(3))) unsigned int*)l, 16, 0, 0);
}

// ---------------- init: widx = -1 ----------------
__global__ void k_init(int* widx, int Wd) {
    int i = blockIdx.x * 256 + threadIdx.x;
    if (i < Wd) widx[i] = -1;
}

__global__ void k_scatter(const int* __restrict__ wmask, int* widx, int L, int Wd) {
    int i = blockIdx.x * 256 + threadIdx.x;
    if (i < L) {
        int m = wmask[i];
        if (m > 0 && m <= Wd) atomicMax(&widx[m - 1], i);  // last token wins
    }
}

// build we directly as hi/lo bf16 split
__global__ void k_build_we_split(const float4* __restrict__ tok, const int* __restrict__ widx,
                                 us* __restrict__ weh, us* __restrict__ wel, int Wd) {
    int i = blockIdx.x * 256 + threadIdx.x;   // over Wd * 192
    if (i >= Wd * 192) return;
    int w = i / 192, c4 = i - w * 192;
    int idx = widx[w];
    float4 v = (idx >= 0) ? tok[idx * 192 + c4] : float4{0.f, 0.f, 0.f, 0.f};
    us hh[4], ll[4];
    split1(v.x, hh[0], ll[0]);
    split1(v.y, hh[1], ll[1]);
    split1(v.z, hh[2], ll[2]);
    split1(v.w, hh[3], ll[3]);
    size_t o = (size_t)w * Hd + c4 * 4;
    *(ushort4*)&weh[o] = ushort4{hh[0], hh[1], hh[2], hh[3]};
    *(ushort4*)&wel[o] = ushort4{ll[0], ll[1], ll[2], ll[3]};
}

// ---------- batched transpose + split: T[n][k]; fmt=0 bf16 hi/lo, fmt=1 fp16 (Th only) ----------
struct TSArgs {
    const float* src[5];
    us* th[5];
    us* tl[5];
    int ld[5];
    int N[5];
    int fmt[5];
};
__global__ __launch_bounds__(256)
void k_tsplit(TSArgs a) {
    __shared__ float tile[64][65];
    const int z = blockIdx.z;
    const int n0 = blockIdx.x * 64, k0 = blockIdx.y * 64;
    if (n0 >= a.N[z]) return;
    const float* W = a.src[z];
    const int ld = a.ld[z];
    for (int idx = threadIdx.x; idx < 4096; idx += 256) {
        int kk = idx >> 6, nn = idx & 63;
        tile[kk][nn] = W[(size_t)(k0 + kk) * ld + n0 + nn];
    }
    __syncthreads();
    us* Th = a.th[z];
    us* Tl = a.tl[z];
    const int fmt = a.fmt[z];
    for (int idx = threadIdx.x; idx < 4096; idx += 256) {
        int nn = idx >> 6, kk = idx & 63;
        size_t o = (size_t)(n0 + nn) * Hd + k0 + kk;
        if (fmt) {
            Th[o] = f2h(tile[kk][nn]);
        } else {
            us h, l;
            split1(tile[kk][nn], h, l);
            Th[o] = h;
            Tl[o] = l;
        }
    }
}

// ---------- row-major hi/lo split ----------
__global__ __launch_bounds__(256)
void k_split(const float* __restrict__ x, int lda, int cols,
             us* __restrict__ h, us* __restrict__ l, int n4) {
    int i = blockIdx.x * 256 + threadIdx.x;
    if (i >= n4) return;
    int c4 = cols >> 2;
    int row = i / c4, cc = (i - row * c4) * 4;
    float4 v = *(const float4*)&x[(size_t)row * lda + cc];
    us hh[4], ll[4];
    split1(v.x, hh[0], ll[0]);
    split1(v.y, hh[1], ll[1]);
    split1(v.z, hh[2], ll[2]);
    split1(v.w, hh[3], ll[3]);
    size_t o = (size_t)row * cols + cc;
    *(ushort4*)&h[o] = ushort4{hh[0], hh[1], hh[2], hh[3]};
    *(ushort4*)&l[o] = ushort4{ll[0], ll[1], ll[2], ll[3]};
}

// ---------- split-bf16 GEMM, LDS double-buffered, K-split partials (small Ms) ----------
__global__ __launch_bounds__(256)
void k_gemm2(const us* __restrict__ Ah, const us* __restrict__ Al,
             const us* __restrict__ BhT, const us* __restrict__ BlT,
             float* __restrict__ Cpart, int M, int N, int K) {
    __shared__ __align__(16) us S[2][4][64 * 32];
    const int tid = threadIdx.x, wave = tid >> 6, lane = tid & 63;
    const int quad = lane >> 4, l15 = lane & 15;
    const int wm = wave & 1, wn = wave >> 1;
    const int m0 = blockIdx.y * 64, n0 = blockIdx.x * 64;
    const int Ks = K / gridDim.z, kbeg = blockIdx.z * Ks, kend = kbeg + Ks;
    float* C = Cpart + (size_t)blockIdx.z * M * N;

    const int srow = wave * 16 + (lane >> 2), soff = (lane & 3) * 8;
    const size_t gaB = (size_t)(m0 + srow) * K + soff;
    const size_t gbB = (size_t)(n0 + srow) * K + soff;
    const int lo = wave * 16 * 32;

    f32x4 acc[2][2];
#pragma unroll
    for (int a = 0; a < 2; ++a)
#pragma unroll
        for (int b = 0; b < 2; ++b) acc[a][b] = (f32x4){0.f, 0.f, 0.f, 0.f};

    auto stage = [&](int p, int k0) {
        gload16(Ah + gaB + k0, &S[p][0][lo]);
        gload16(Al + gaB + k0, &S[p][1][lo]);
        gload16(BhT + gbB + k0, &S[p][2][lo]);
        gload16(BlT + gbB + k0, &S[p][3][lo]);
    };

    int p = 0;
    stage(0, kbeg);
    for (int k0 = kbeg; k0 < kend; k0 += 32) {
        __syncthreads();
        if (k0 + 32 < kend) stage(p ^ 1, k0 + 32);
        short8 ah[2], al[2], bh[2], bl[2];
#pragma unroll
        for (int mt = 0; mt < 2; ++mt) {
            int off = (wm * 32 + mt * 16 + l15) * 32 + quad * 8;
            ah[mt] = *(const short8*)&S[p][0][off];
            al[mt] = *(const short8*)&S[p][1][off];
        }
#pragma unroll
        for (int nt = 0; nt < 2; ++nt) {
            int off = (wn * 32 + nt * 16 + l15) * 32 + quad * 8;
            bh[nt] = *(const short8*)&S[p][2][off];
            bl[nt] = *(const short8*)&S[p][3][off];
        }
#pragma unroll
        for (int mt = 0; mt < 2; ++mt)
#pragma unroll
            for (int nt = 0; nt < 2; ++nt) {
                acc[mt][nt] = __builtin_amdgcn_mfma_f32_16x16x32_bf16(al[mt], bh[nt], acc[mt][nt], 0, 0, 0);
                acc[mt][nt] = __builtin_amdgcn_mfma_f32_16x16x32_bf16(ah[mt], bl[nt], acc[mt][nt], 0, 0, 0);
                acc[mt][nt] = __builtin_amdgcn_mfma_f32_16x16x32_bf16(ah[mt], bh[nt], acc[mt][nt], 0, 0, 0);
            }
        p ^= 1;
    }
#pragma unroll
    for (int mt = 0; mt < 2; ++mt)
#pragma unroll
        for (int nt = 0; nt < 2; ++nt) {
            int col = n0 + wn * 32 + nt * 16 + l15;
#pragma unroll
            for (int reg = 0; reg < 4; ++reg) {
                int row = m0 + wm * 32 + mt * 16 + quad * 4 + reg;
                C[(size_t)row * N + col] = acc[mt][nt][reg];
            }
        }
}

// ---------- split-bf16 GEMM, z=1, fused outputs (bias + f32 / hi-lo split / 16-bit) ----------
__global__ __launch_bounds__(256)
void k_gemm3(const us* __restrict__ Ah, const us* __restrict__ Al,
             const us* __restrict__ BhT, const us* __restrict__ BlT,
             const float* __restrict__ bias, float* __restrict__ outF,
             us* __restrict__ sh, us* __restrict__ sl, us* __restrict__ bh16,
             int fp16out, int scols, int N, int K) {
    __shared__ __align__(16) us S[2][4][64 * 32];
    const int tid = threadIdx.x, wave = tid >> 6, lane = tid & 63;
    const int quad = lane >> 4, l15 = lane & 15;
    const int wm = wave & 1, wn = wave >> 1;
    const int m0 = blockIdx.y * 64, n0 = blockIdx.x * 64;

    const int srow = wave * 16 + (lane >> 2), soff = (lane & 3) * 8;
    const size_t gaB = (size_t)(m0 + srow) * K + soff;
    const size_t gbB = (size_t)(n0 + srow) * K + soff;
    const int lo = wave * 16 * 32;

    f32x4 acc[2][2];
#pragma unroll
    for (int a = 0; a < 2; ++a)
#pragma unroll
        for (int b = 0; b < 2; ++b) acc[a][b] = (f32x4){0.f, 0.f, 0.f, 0.f};

    auto stage = [&](int p, int k0) {
        gload16(Ah + gaB + k0, &S[p][0][lo]);
        gload16(Al + gaB + k0, &S[p][1][lo]);
        gload16(BhT + gbB + k0, &S[p][2][lo]);
        gload16(BlT + gbB + k0, &S[p][3][lo]);
    };

    int p = 0;
    stage(0, 0);
    for (int k0 = 0; k0 < K; k0 += 32) {
        __syncthreads();
        if (k0 + 32 < K) stage(p ^ 1, k0 + 32);
        short8 ah[2], al[2], bh[2], bl[2];
#pragma unroll
        for (int mt = 0; mt < 2; ++mt) {
            int off = (wm * 32 + mt * 16 + l15) * 32 + quad * 8;
            ah[mt] = *(const short8*)&S[p][0][off];
            al[mt] = *(const short8*)&S[p][1][off];
        }
#pragma unroll
        for (int nt = 0; nt < 2; ++nt) {
            int off = (wn * 32 + nt * 16 + l15) * 32 + quad * 8;
            bh[nt] = *(const short8*)&S[p][2][off];
            bl[nt] = *(const short8*)&S[p][3][off];
        }
#pragma unroll
        for (int mt = 0; mt < 2; ++mt)
#pragma unroll
            for (int nt = 0; nt < 2; ++nt) {
                acc[mt][nt] = __builtin_amdgcn_mfma_f32_16x16x32_bf16(al[mt], bh[nt], acc[mt][nt], 0, 0, 0);
                acc[mt][nt] = __builtin_amdgcn_mfma_f32_16x16x32_bf16(ah[mt], bl[nt], acc[mt][nt], 0, 0, 0);
                acc[mt][nt] = __builtin_amdgcn_mfma_f32_16x16x32_bf16(ah[mt], bh[nt], acc[mt][nt], 0, 0, 0);
            }
        p ^= 1;
    }
#pragma unroll
    for (int mt = 0; mt < 2; ++mt)
#pragma unroll
        for (int nt = 0; nt < 2; ++nt) {
            int col = n0 + wn * 32 + nt * 16 + l15;
            float bb = bias ? bias[col] : 0.f;
#pragma unroll
            for (int reg = 0; reg < 4; ++reg) {
                int row = m0 + wm * 32 + mt * 16 + quad * 4 + reg;
                float v = acc[mt][nt][reg] + bb;
                if (outF) outF[(size_t)row * N + col] = v;
                if (sh) {
                    if (col < scols) {
                        us h, l;
                        split1(v, h, l);
                        size_t o = (size_t)row * scols + col;
                        sh[o] = h;
                        sl[o] = l;
                    } else if (bh16) {
                        bh16[(size_t)row * scols + (col - scols)] = fp16out ? f2h(v) : f2b(v);
                    }
                }
            }
        }
}

// ---------- reduce partials + bias; f32 out + hi/lo split (col<scols) + 16-bit (col>=scols) ----------
__global__ __launch_bounds__(256)
void k_reduce(const float* __restrict__ part, int S, int MN, int N,
              const float* __restrict__ bias, float* __restrict__ outF,
              us* __restrict__ sh, us* __restrict__ sl, int scols,
              us* __restrict__ bh16, int fp16out) {
    int i = blockIdx.x * 256 + threadIdx.x;
    if (i >= MN) return;
    float v = 0.f;
    for (int s = 0; s < S; ++s) v += part[(size_t)s * MN + i];
    int row = i / N, col = i - row * N;
    if (bias) v += bias[col];
    if (outF) outF[i] = v;
    if (col < scols) {
        if (sh) {
            us h, l;
            split1(v, h, l);
            size_t o = (size_t)row * scols + col;
            sh[o] = h;
            sl[o] = l;
        }
    } else if (bh16) {
        bh16[(size_t)row * scols + (col - scols)] = fp16out ? f2h(v) : f2b(v);
    }
}

// ---------------- P-GEMM v7c (best known, R15): fp16 operands, packed-mul fused lb1-scaling ----------------
// L2-locality decode, reg->LDS->MFMA single-barrier pipeline, XOR swizzle, 3 blocks/CU.
// Retired levers (all regressed): (256,4) occupancy (spills, R14); B-direct-from-global
// (R6/R12/R16); bigger wave tiles (R12); K-split prelims (R17).
__global__ __launch_bounds__(256, 3)
void k_mfma7(const us* __restrict__ t1b,   // (1024,768) fp16
             const us* __restrict__ W1ct,  // (768,768) fp16 [j][k]
             const us* __restrict__ lb1b,  // (64,768) fp16
             const float* __restrict__ Aw, // (1024,768) f32
             const float* __restrict__ Bc, // (64,768) f32 (includes b1)
             const float* __restrict__ W2, // (768,3) f32
             float* __restrict__ scr) {    // (6,1024,64,3) f32 partials
    __shared__ __align__(16) us As[2][128 * 32];
    __shared__ __align__(16) us Bs[2][128 * 32];
    __shared__ float sred[128 * 3];

    const int tid = threadIdx.x, wave = tid >> 6, lane = tid & 63;
    const int quad = lane >> 4, l15 = lane & 15;
    const int wm = wave & 1, wn = wave >> 1;

    // L2-locality decode: b = xcd + 8*(jx*64 + c); my = xcd
    const int b = blockIdx.x;
    const int xcd = b & 7, slot = b >> 3;    // slot 0..383
    const int jx = slot >> 6;                // 0..5
    const int c = slot & 63;                 // 0..63 (varies fastest)
    const int my = xcd;                      // 0..7
    const int jt = jx * 128, m0 = my * 128;

    for (int i = tid; i < 128 * 3; i += 256) sred[i] = 0.f;

    // staging map: thread -> row aro (0..127), 16 contiguous k at kbase
    const int aro = tid >> 1;
    const int qb = (tid & 1) * 2;            // logical chunk pair {qb, qb+1}
    const int kbase = qb * 8;
    const us* gA = W1ct + (size_t)(jt + aro) * Hd + kbase;
    const us* gL = lb1b + (size_t)c * Hd + kbase;
    const us* gB = t1b + (size_t)(m0 + aro) * Hd + kbase;
    const int w0 = swz(aro, qb), w1 = swz(aro, qb + 1);

    f32x4 acc[4][4];
#pragma unroll
    for (int mt = 0; mt < 4; ++mt)
#pragma unroll
        for (int nt = 0; nt < 4; ++nt) acc[mt][nt] = (f32x4){0.f, 0.f, 0.f, 0.f};

    // raw staging registers, two sets
    short8 aw0l, aw0h, al0l, al0h, b0l, b0h;
    short8 aw1l, aw1h, al1l, al1h, b1l, b1h;

    // prologue: set0 <- k=0; set1 <- k=32; scale+publish set0 -> buf0
    aw0l = *(const short8*)(gA + 0);  aw0h = *(const short8*)(gA + 8);
    al0l = *(const short8*)(gL + 0);  al0h = *(const short8*)(gL + 8);
    b0l  = *(const short8*)(gB + 0);  b0h  = *(const short8*)(gB + 8);
    aw1l = *(const short8*)(gA + 32); aw1h = *(const short8*)(gA + 40);
    al1l = *(const short8*)(gL + 32); al1h = *(const short8*)(gL + 40);
    b1l  = *(const short8*)(gB + 32); b1h  = *(const short8*)(gB + 40);
    *(short8*)&As[0][w0] = hmul8(aw0l, al0l);
    *(short8*)&As[0][w1] = hmul8(aw0h, al0h);
    *(short8*)&Bs[0][w0] = b0l;
    *(short8*)&Bs[0][w1] = b0h;
    __syncthreads();

    for (int k = 0; k < Hd; k += 64) {
        // ---- step A: compute k from buf0; set1 holds raw k+32 ----
        {
            short8 af[4], bf[4];
#pragma unroll
            for (int mt = 0; mt < 4; ++mt)
                af[mt] = *(const short8*)&As[0][swz(wm * 64 + mt * 16 + l15, quad)];
#pragma unroll
            for (int nt = 0; nt < 4; ++nt)
                bf[nt] = *(const short8*)&Bs[0][swz(wn * 64 + nt * 16 + l15, quad)];
            if (k + 64 < Hd) {            // prefetch raw k+64 into set0
                aw0l = *(const short8*)(gA + k + 64); aw0h = *(const short8*)(gA + k + 72);
                al0l = *(const short8*)(gL + k + 64); al0h = *(const short8*)(gL + k + 72);
                b0l  = *(const short8*)(gB + k + 64); b0h  = *(const short8*)(gB + k + 72);
            }
#pragma unroll
            for (int mt = 0; mt < 4; ++mt)
#pragma unroll
                for (int nt = 0; nt < 4; ++nt)
                    acc[mt][nt] = __builtin_amdgcn_mfma_f32_16x16x32_f16(
                        __builtin_bit_cast(half8, af[mt]),
                        __builtin_bit_cast(half8, bf[nt]), acc[mt][nt], 0, 0, 0);
            *(short8*)&As[1][w0] = hmul8(aw1l, al1l);   // scale+publish k+32
            *(short8*)&As[1][w1] = hmul8(aw1h, al1h);
            *(short8*)&Bs[1][w0] = b1l;
            *(short8*)&Bs[1][w1] = b1h;
            __syncthreads();
        }
        // ---- step B: compute k+32 from buf1; set0 holds raw k+64 ----
        {
            short8 af[4], bf[4];
#pragma unroll
            for (int mt = 0; mt < 4; ++mt)
                af[mt] = *(const short8*)&As[1][swz(wm * 64 + mt * 16 + l15, quad)];
#pragma unroll
            for (int nt = 0; nt < 4; ++nt)
                bf[nt] = *(const short8*)&Bs[1][swz(wn * 64 + nt * 16 + l15, quad)];
            if (k + 96 < Hd) {            // prefetch raw k+96 into set1
                aw1l = *(const short8*)(gA + k + 96); aw1h = *(const short8*)(gA + k + 104);
                al1l = *(const short8*)(gL + k + 96); al1h = *(const short8*)(gL + k + 104);
                b1l  = *(const short8*)(gB + k + 96); b1h  = *(const short8*)(gB + k + 104);
            }
#pragma unroll
            for (int mt = 0; mt < 4; ++mt)
#pragma unroll
                for (int nt = 0; nt < 4; ++nt)
                    acc[mt][nt] = __builtin_amdgcn_mfma_f32_16x16x32_f16(
                        __builtin_bit_cast(half8, af[mt]),
                        __builtin_bit_cast(half8, bf[nt]), acc[mt][nt], 0, 0, 0);
            if (k + 64 < Hd) {
                *(short8*)&As[0][w0] = hmul8(aw0l, al0l);   // scale+publish k+64
                *(short8*)&As[0][w1] = hmul8(aw0h, al0h);
                *(short8*)&Bs[0][w0] = b0l;
                *(short8*)&Bs[0][w1] = b0h;
                __syncthreads();
            }
        }
    }

    // ---- epilogue: h = relu(P + Aw + Bc); sacc[w][r] += h*W2[j][r] ----
    // j = jt + wm*64 + mt*16 + quad*4 + reg ; w = m0 + wn*64 + nt*16 + l15
    float bcv[4][4], w2v[4][4][3];
#pragma unroll
    for (int mt = 0; mt < 4; ++mt) {
        const int jb = jt + wm * 64 + mt * 16 + quad * 4;
        float4 b4 = *(const float4*)&Bc[(size_t)c * Hd + jb];
        bcv[mt][0] = b4.x; bcv[mt][1] = b4.y; bcv[mt][2] = b4.z; bcv[mt][3] = b4.w;
#pragma unroll
        for (int reg = 0; reg < 4; ++reg)
#pragma unroll
            for (int r = 0; r < 3; ++r) w2v[mt][reg][r] = W2[(jb + reg) * 3 + r];
    }
#pragma unroll
    for (int nt = 0; nt < 4; ++nt) {
        const int w = m0 + wn * 64 + nt * 16 + l15;
        const float* awp = Aw + (size_t)w * Hd + jt + wm * 64;
        float s0 = 0.f, s1 = 0.f, s2 = 0.f;
#pragma unroll
        for (int mt = 0; mt < 4; ++mt) {
            float4 a4 = *(const float4*)&awp[mt * 16 + quad * 4];
            float av[4] = {a4.x, a4.y, a4.z, a4.w};
#pragma unroll
            for (int reg = 0; reg < 4; ++reg) {
                float h = acc[mt][nt][reg] + av[reg] + bcv[mt][reg];
                h = h > 0.f ? h : 0.f;
                s0 += h * w2v[mt][reg][0];
                s1 += h * w2v[mt][reg][1];
                s2 += h * w2v[mt][reg][2];
            }
        }
        s0 += __shfl_xor(s0, 16); s0 += __shfl_xor(s0, 32);
        s1 += __shfl_xor(s1, 16); s1 += __shfl_xor(s1, 32);
        s2 += __shfl_xor(s2, 16); s2 += __shfl_xor(s2, 32);
        if (quad == 0) {
            const int wl = wn * 64 + nt * 16 + l15;
            atomicAdd(&sred[wl * 3 + 0], s0);   // LDS, 2-way (wm)
            atomicAdd(&sred[wl * 3 + 1], s1);
            atomicAdd(&sred[wl * 3 + 2], s2);
        }
    }
    __syncthreads();
    // non-atomic store to per-jx scratch slot (disjoint across blocks)
    float* slab = scr + ((size_t)jx * 1024 * Cn + (size_t)m0 * Cn + c) * 3;
    for (int i = tid; i < 128 * 3; i += 256) {
        int wl = i / 3, r = i - wl * 3;
        slab[(size_t)wl * Cn * 3 + r] = sred[i];
    }
}

// ---------- final: out = b2 + sum_jx scr[jx] ----------
__global__ __launch_bounds__(256)
void k_scores(const float* __restrict__ scr, const float* __restrict__ b2,
              float* __restrict__ out, int n) {
    int i = blockIdx.x * 256 + threadIdx.x;
    if (i >= n) return;
    float v = b2[i % 3];
#pragma unroll
    for (int s = 0; s < 6; ++s) v += scr[(size_t)s * n + i];
    out[i] = v;
}

extern "C" void kernel_launch(void* const* d_in, const int* in_sizes, int n_in,
                              void* d_out, int out_size, void* d_ws, size_t ws_size,
                              hipStream_t stream) {
    const float* tok    = (const float*)d_in[0];
    const int*   wmask  = (const int*)d_in[1];
    const float* labe   = (const float*)d_in[3];
    const float* W_tok  = (const float*)d_in[4];
    const float* b_tok  = (const float*)d_in[5];
    const float* W_lab  = (const float*)d_in[6];
    const float* b_lab  = (const float*)d_in[7];
    const float* W1     = (const float*)d_in[8];
    const float* b1     = (const float*)d_in[9];
    const float* W2     = (const float*)d_in[10];
    const float* b2     = (const float*)d_in[11];
    float* out = (float*)d_out;

    const int L  = in_sizes[1];
    const int Wd = out_size / (Cn * 3);   // 1024

    char* ws = (char*)d_ws;
    size_t off = 0;
    auto alloc = [&](size_t bytes) { char* p = ws + off; off += (bytes + 255) & ~(size_t)255; return p; };
    // ---- persistent region ----
    int*   widx  = (int*)alloc(4096);
    float* Abuf  = (float*)alloc((size_t)Wd * Hd * 4);
    float* Bbuf  = (float*)alloc((size_t)Cn * Hd * 4);
    us* W1ct  = (us*)alloc((size_t)Hd * Hd * 2);   // fp16
    us* W1cl  = (us*)alloc((size_t)Hd * Hd * 2);   // unused
    us* t1b   = (us*)alloc((size_t)Wd * Hd * 2);   // fp16
    us* lb1b  = (us*)alloc((size_t)Cn * Hd * 2);   // fp16
    float* scr = (float*)alloc((size_t)6 * Wd * Cn * 3 * 4);   // 4.72 MB partials
    // ---- scratch region ----
    us* WtTh  = (us*)alloc((size_t)H2 * Hd * 2);
    us* WtTl  = (us*)alloc((size_t)H2 * Hd * 2);
    us* WlTh  = (us*)alloc((size_t)H2 * Hd * 2);
    us* WlTl  = (us*)alloc((size_t)H2 * Hd * 2);
    us* W1aTh = (us*)alloc((size_t)Hd * Hd * 2);
    us* W1aTl = (us*)alloc((size_t)Hd * Hd * 2);
    us* W1bTh = (us*)alloc((size_t)Hd * Hd * 2);
    us* W1bTl = (us*)alloc((size_t)Hd * Hd * 2);
    us* weh   = (us*)alloc((size_t)Wd * Hd * 2);
    us* wel   = (us*)alloc((size_t)Wd * Hd * 2);
    us* lah   = (us*)alloc((size_t)Cn * Hd * 2);
    us* lal   = (us*)alloc((size_t)Cn * Hd * 2);
    us* t0h   = (us*)alloc((size_t)Wd * Hd * 2);
    us* t0l   = (us*)alloc((size_t)Wd * Hd * 2);
    us* lb0h  = (us*)alloc((size_t)Cn * Hd * 2);
    us* lb0l  = (us*)alloc((size_t)Cn * Hd * 2);
    float* part = (float*)alloc((size_t)8 * Cn * H2 * 4);

    // 1) init + scatter + we split
    k_init<<<(Wd + 255) / 256, 256, 0, stream>>>(widx, Wd);
    k_scatter<<<(L + 255) / 256, 256, 0, stream>>>(wmask, widx, L, Wd);
    k_build_we_split<<<(Wd * 192 + 255) / 256, 256, 0, stream>>>((const float4*)tok, widx, weh, wel, Wd);

    // 2) batched weight transpose+split (W1c -> fp16)
    TSArgs ts;
    ts.src[0] = W_tok;  ts.th[0] = WtTh;  ts.tl[0] = WtTl;  ts.ld[0] = H2; ts.N[0] = H2; ts.fmt[0] = 0;
    ts.src[1] = W_lab;  ts.th[1] = WlTh;  ts.tl[1] = WlTl;  ts.ld[1] = H2; ts.N[1] = H2; ts.fmt[1] = 0;
    ts.src[2] = W1;                         ts.th[2] = W1aTh; ts.tl[2] = W1aTl; ts.ld[2] = Hd; ts.N[2] = Hd; ts.fmt[2] = 0;
    ts.src[3] = W1 + (size_t)Hd * Hd;       ts.th[3] = W1bTh; ts.tl[3] = W1bTl; ts.ld[3] = Hd; ts.N[3] = Hd; ts.fmt[3] = 0;
    ts.src[4] = W1 + (size_t)2 * Hd * Hd;   ts.th[4] = W1ct;  ts.tl[4] = W1cl;  ts.ld[4] = Hd; ts.N[4] = Hd; ts.fmt[4] = 1;
    k_tsplit<<<dim3(H2 / 64, Hd / 64, 5), 256, 0, stream>>>(ts);

    // 3) label emb split
    k_split<<<(Cn * Hd / 4 + 255) / 256, 256, 0, stream>>>(labe, Hd, Hd, lah, lal, Cn * Hd / 4);

    // 4) t = we @ W_tok + b_tok -> fused t0 hi/lo + t1b fp16
    k_gemm3<<<dim3(H2 / 64, Wd / 64), 256, 0, stream>>>(weh, wel, WtTh, WtTl, b_tok,
                                                        nullptr, t0h, t0l, t1b, 1, Hd, H2, Hd);

    // 5) lb = labe @ W_lab + b_lab (64x1536), z=8 -> reduce (lb0 split + lb1b fp16)
    k_gemm2<<<dim3(H2 / 64, 1, 8), 256, 0, stream>>>(lah, lal, WlTh, WlTl, part, Cn, H2, Hd);
    k_reduce<<<(Cn * H2 + 255) / 256, 256, 0, stream>>>(part, 8, Cn * H2, H2, b_lab, nullptr, lb0h, lb0l, Hd, lb1b, 1);

    // 6) Aw = t0 @ W1a (1024x768) -> fused f32 write
    k_gemm3<<<dim3(Hd / 64, Wd / 64), 256, 0, stream>>>(t0h, t0l, W1aTh, W1aTl, nullptr,
                                                        Abuf, nullptr, nullptr, nullptr, 0, 0, Hd, Hd);

    // 7) Bc = lb0 @ W1b + b1 (64x768), z=8 -> reduce
    k_gemm2<<<dim3(Hd / 64, 1, 8), 256, 0, stream>>>(lb0h, lb0l, W1bTh, W1bTl, part, Cn, Hd, Hd);
    k_reduce<<<(Cn * Hd + 255) / 256, 256, 0, stream>>>(part, 8, Cn * Hd, Hd, b1, Bbuf, nullptr, nullptr, Hd, nullptr, 0);

    // 8) fused fp16 P-GEMM (all 64 c, one dispatch, L2-locality decode) -> scratch
    k_mfma7<<<3072, 256, 0, stream>>>(t1b, W1ct, lb1b, Abuf, Bbuf, W2, scr);

    // 9) out = b2 + sum_jx scr
    k_scores<<<(Wd * Cn * 3 + 255) / 256, 256, 0, stream>>>(scr, b2, out, Wd * Cn * 3);
}